// Round 2
// baseline (217.788 us; speedup 1.0000x reference)
//
#include <hip/hip_runtime.h>

#define NB 16
#define BATCHES 4

struct WS {
    unsigned int mm[16];                         // per batch: fminEnc, fmaxEnc, mminEnc, mmaxEnc
    unsigned long long joint[BATCHES * 256];     // fixed-point (x 2^32) joint histogram [b][f][m]
    unsigned int fcount[BATCHES * NB];           // exact integer fixed-bin counts
};

// order-preserving float<->uint encoding
__device__ __forceinline__ unsigned int fenc(float x) {
    unsigned int u = __float_as_uint(x);
    return (u & 0x80000000u) ? ~u : (u | 0x80000000u);
}
__device__ __forceinline__ float fdec(unsigned int u) {
    unsigned int v = (u & 0x80000000u) ? (u ^ 0x80000000u) : ~u;
    return __uint_as_float(v);
}

__global__ __launch_bounds__(256) void k_init(WS* ws) {
    int t = threadIdx.x;
    if (t < 16) ws->mm[t] = (t & 1) ? 0u : 0xFFFFFFFFu;
    for (int i = t; i < BATCHES * 256; i += 256) ws->joint[i] = 0ull;
    for (int i = t; i < BATCHES * NB; i += 256) ws->fcount[i] = 0u;
}

__global__ __launch_bounds__(256) void k_minmax(const float4* __restrict__ mov,
                                                const float4* __restrict__ fix,
                                                WS* __restrict__ ws, int nvec) {
    int b = blockIdx.y;
    const float4* m4 = mov + (size_t)b * nvec;
    const float4* f4 = fix + (size_t)b * nvec;
    int stride = gridDim.x * blockDim.x;
    int i = blockIdx.x * blockDim.x + threadIdx.x;
    float fmn = 3.4e38f, fmx = -3.4e38f, mmn = 3.4e38f, mmx = -3.4e38f;

    // 4x unrolled: 8 float4 loads in flight per iteration
    for (; i + 3 * stride < nvec; i += 4 * stride) {
        float4 f0 = f4[i], f1 = f4[i + stride], f2 = f4[i + 2 * stride], f3 = f4[i + 3 * stride];
        float4 m0 = m4[i], m1 = m4[i + stride], m2 = m4[i + 2 * stride], m3 = m4[i + 3 * stride];
        fmn = fminf(fmn, fminf(fminf(fminf(f0.x, f0.y), fminf(f0.z, f0.w)),
                               fminf(fminf(f1.x, f1.y), fminf(f1.z, f1.w))));
        fmn = fminf(fmn, fminf(fminf(fminf(f2.x, f2.y), fminf(f2.z, f2.w)),
                               fminf(fminf(f3.x, f3.y), fminf(f3.z, f3.w))));
        fmx = fmaxf(fmx, fmaxf(fmaxf(fmaxf(f0.x, f0.y), fmaxf(f0.z, f0.w)),
                               fmaxf(fmaxf(f1.x, f1.y), fmaxf(f1.z, f1.w))));
        fmx = fmaxf(fmx, fmaxf(fmaxf(fmaxf(f2.x, f2.y), fmaxf(f2.z, f2.w)),
                               fmaxf(fmaxf(f3.x, f3.y), fmaxf(f3.z, f3.w))));
        mmn = fminf(mmn, fminf(fminf(fminf(m0.x, m0.y), fminf(m0.z, m0.w)),
                               fminf(fminf(m1.x, m1.y), fminf(m1.z, m1.w))));
        mmn = fminf(mmn, fminf(fminf(fminf(m2.x, m2.y), fminf(m2.z, m2.w)),
                               fminf(fminf(m3.x, m3.y), fminf(m3.z, m3.w))));
        mmx = fmaxf(mmx, fmaxf(fmaxf(fmaxf(m0.x, m0.y), fmaxf(m0.z, m0.w)),
                               fmaxf(fmaxf(m1.x, m1.y), fmaxf(m1.z, m1.w))));
        mmx = fmaxf(mmx, fmaxf(fmaxf(fmaxf(m2.x, m2.y), fmaxf(m2.z, m2.w)),
                               fmaxf(fmaxf(m3.x, m3.y), fmaxf(m3.z, m3.w))));
    }
    for (; i < nvec; i += stride) {
        float4 f = f4[i];
        float4 m = m4[i];
        fmn = fminf(fmn, fminf(fminf(f.x, f.y), fminf(f.z, f.w)));
        fmx = fmaxf(fmx, fmaxf(fmaxf(f.x, f.y), fmaxf(f.z, f.w)));
        mmn = fminf(mmn, fminf(fminf(m.x, m.y), fminf(m.z, m.w)));
        mmx = fmaxf(mmx, fmaxf(fmaxf(m.x, m.y), fmaxf(m.z, m.w)));
    }

    __shared__ float4 red[256];
    int t = threadIdx.x;
    red[t] = make_float4(fmn, fmx, mmn, mmx);
    __syncthreads();
    for (int s = 128; s > 0; s >>= 1) {
        if (t < s) {
            float4 a = red[t], c = red[t + s];
            red[t] = make_float4(fminf(a.x, c.x), fmaxf(a.y, c.y),
                                 fminf(a.z, c.z), fmaxf(a.w, c.w));
        }
        __syncthreads();
    }
    if (t == 0) {
        float4 r = red[0];
        atomicMin(&ws->mm[b * 4 + 0], fenc(r.x));
        atomicMax(&ws->mm[b * 4 + 1], fenc(r.y));
        atomicMin(&ws->mm[b * 4 + 2], fenc(r.z));
        atomicMax(&ws->mm[b * 4 + 3], fenc(r.w));
    }
}

__global__ __launch_bounds__(256) void k_hist(const float4* __restrict__ mov,
                                              const float4* __restrict__ fix,
                                              WS* __restrict__ ws, int nvec) {
    __shared__ unsigned long long ldsJ[4][256];   // one copy per wave
    __shared__ unsigned int ldsF[NB];
    int t = threadIdx.x;
    int b = blockIdx.y;

    for (int i = t; i < 1024; i += 256) ((unsigned long long*)ldsJ)[i] = 0ull;
    if (t < NB) ldsF[t] = 0u;

    float fmin_ = fdec(ws->mm[b * 4 + 0]);
    float fmax_ = fdec(ws->mm[b * 4 + 1]);
    float mmin_ = fdec(ws->mm[b * 4 + 2]);
    float mmax_ = fdec(ws->mm[b * 4 + 3]);
    float fbs = (fmax_ - fmin_) / 12.0f;
    float mbs = (mmax_ - mmin_) / 12.0f;
    float fsh = fmin_ / fbs - 2.0f;
    float msh = mmin_ / mbs - 2.0f;
    __syncthreads();

    int copy = t >> 6;
    const float4* m4 = mov + (size_t)b * nvec;
    const float4* f4 = fix + (size_t)b * nvec;
    int stride = gridDim.x * blockDim.x;

    auto proc = [&](float fv, float mv) {
        float fterm = fv / fbs - fsh;
        int fi = (int)fterm;
        fi = fi < 2 ? 2 : (fi > NB - 3 ? NB - 3 : fi);
        float mterm = mv / mbs - msh;
        int mi_ = (int)mterm;
        mi_ = mi_ < 2 ? 2 : (mi_ > NB - 3 ? NB - 3 : mi_);
        atomicAdd(&ldsF[fi], 1u);
        float b0 = (float)(mi_ - 1) - mterm;
        int baseIdx = fi * NB + mi_ - 1;
#pragma unroll
        for (int k = 0; k < 4; k++) {
            float u = b0 + (float)k;
            float au = fabsf(u);
            float su = au * au;
            float w;
            if (au < 1.0f)
                w = (4.0f - 6.0f * su + 3.0f * su * au) * (1.0f / 6.0f);
            else if (au < 2.0f)
                w = (8.0f - 12.0f * au + 6.0f * su - su * au) * (1.0f / 6.0f);
            else
                w = 0.0f;
            w = fmaxf(w, 0.0f);
            unsigned long long q = (unsigned long long)((double)w * 4294967296.0);
            atomicAdd(&ldsJ[copy][baseIdx + k], q);
        }
    };

    int i = blockIdx.x * blockDim.x + t;
    for (; i + stride < nvec; i += 2 * stride) {
        float4 f0 = f4[i], f1 = f4[i + stride];
        float4 m0 = m4[i], m1 = m4[i + stride];
        proc(f0.x, m0.x); proc(f0.y, m0.y); proc(f0.z, m0.z); proc(f0.w, m0.w);
        proc(f1.x, m1.x); proc(f1.y, m1.y); proc(f1.z, m1.z); proc(f1.w, m1.w);
    }
    for (; i < nvec; i += stride) {
        float4 fv = f4[i];
        float4 mv = m4[i];
        proc(fv.x, mv.x); proc(fv.y, mv.y); proc(fv.z, mv.z); proc(fv.w, mv.w);
    }
    __syncthreads();

    unsigned long long v = ldsJ[0][t] + ldsJ[1][t] + ldsJ[2][t] + ldsJ[3][t];
    if (v) atomicAdd(&ws->joint[b * 256 + t], v);
    if (t < NB) {
        unsigned int c = ldsF[t];
        if (c) atomicAdd(&ws->fcount[b * NB + t], c);
    }
}

__global__ __launch_bounds__(1024) void k_final(const WS* __restrict__ ws,
                                                float* __restrict__ out, double invN) {
    __shared__ double shp[1024];
    __shared__ double red[1024];
    int t = threadIdx.x;
    int b = t >> 8;          // batch 0..3
    int bin = t & 255;       // joint bin 0..255

    double jt = (double)ws->joint[b * 256 + bin];
    red[t] = jt;
    __syncthreads();
    for (int s = 128; s > 0; s >>= 1) {
        if (bin < s) red[t] += red[t + s];
        __syncthreads();
    }
    double total = red[b * 256];
    __syncthreads();

    double p = jt / total;
    shp[t] = p;
    __syncthreads();

    double val = (p > 0.0) ? p * log(p) : 0.0;
    if (bin < NB) {
        double mp = 0.0;
        for (int f = 0; f < NB; f++) mp += shp[b * 256 + f * NB + bin];
        if (mp > 0.0) val -= mp * log(mp);
        double fp = (double)ws->fcount[b * NB + bin] * invN;
        if (fp > 0.0) val -= fp * log(fp);
    }
    __syncthreads();
    red[t] = val;
    __syncthreads();
    for (int s = 128; s > 0; s >>= 1) {
        if (bin < s) red[t] += red[t + s];
        __syncthreads();
    }
    if (t == 0) {
        double acc = red[0] + red[256] + red[512] + red[768];
        out[0] = (float)(-acc / (double)BATCHES);
    }
}

extern "C" void kernel_launch(void* const* d_in, const int* in_sizes, int n_in,
                              void* d_out, int out_size, void* d_ws, size_t ws_size,
                              hipStream_t stream) {
    const float* mov = (const float*)d_in[0];
    const float* fix = (const float*)d_in[1];
    float* out = (float*)d_out;
    WS* ws = (WS*)d_ws;

    int total = in_sizes[0];
    int N = total / BATCHES;      // 128^3 = 2097152
    int nvec = N / 4;

    k_init<<<1, 256, 0, stream>>>(ws);

    dim3 grid(512, BATCHES);
    k_minmax<<<grid, 256, 0, stream>>>((const float4*)mov, (const float4*)fix, ws, nvec);
    k_hist<<<grid, 256, 0, stream>>>((const float4*)mov, (const float4*)fix, ws, nvec);
    k_final<<<1, 1024, 0, stream>>>(ws, out, 1.0 / (double)N);
}

// Round 7
// 149.691 us; speedup vs baseline: 1.4549x; 1.4549x over previous
//
#include <hip/hip_runtime.h>

#define NB 16
#define BATCHES 4
#define GX 32            // blocks per batch
#define BT 1024          // threads per block

typedef unsigned long long ull;

struct WS {
    float4 slot[BATCHES * GX];        // per-block {fmin, fmax, mmin, mmax}
    ull joint[BATCHES * 256];         // fixed-point (x 2^32) joint histogram
    unsigned int fcount[BATCHES * NB];
};

__global__ __launch_bounds__(BT) void k_minmax(const float4* __restrict__ mov,
                                               const float4* __restrict__ fix,
                                               WS* __restrict__ ws, int nvec) {
    int t = threadIdx.x;
    int b = blockIdx.y, bx = blockIdx.x;
    // block (0,0) zeroes the accumulator region (visible to k_hist at kernel boundary)
    if (bx == 0 && b == 0) {
        if (t < BATCHES * 256) ws->joint[t] = 0ull;       // exactly 1024
        if (t < BATCHES * NB) ws->fcount[t] = 0u;
    }
    const float4* m4 = mov + (size_t)b * nvec;
    const float4* f4 = fix + (size_t)b * nvec;
    int T = gridDim.x * BT;
    int i = bx * BT + t;
    float fmn = 3.4e38f, fmx = -3.4e38f, mmn = 3.4e38f, mmx = -3.4e38f;
    for (; i + 3 * T < nvec; i += 4 * T) {
        float4 f0 = f4[i], f1 = f4[i + T], f2 = f4[i + 2 * T], f3 = f4[i + 3 * T];
        float4 m0 = m4[i], m1 = m4[i + T], m2 = m4[i + 2 * T], m3 = m4[i + 3 * T];
        fmn = fminf(fmn, fminf(fminf(fminf(f0.x, f0.y), fminf(f0.z, f0.w)),
                               fminf(fminf(f1.x, f1.y), fminf(f1.z, f1.w))));
        fmn = fminf(fmn, fminf(fminf(fminf(f2.x, f2.y), fminf(f2.z, f2.w)),
                               fminf(fminf(f3.x, f3.y), fminf(f3.z, f3.w))));
        fmx = fmaxf(fmx, fmaxf(fmaxf(fmaxf(f0.x, f0.y), fmaxf(f0.z, f0.w)),
                               fmaxf(fmaxf(f1.x, f1.y), fmaxf(f1.z, f1.w))));
        fmx = fmaxf(fmx, fmaxf(fmaxf(fmaxf(f2.x, f2.y), fmaxf(f2.z, f2.w)),
                               fmaxf(fmaxf(f3.x, f3.y), fmaxf(f3.z, f3.w))));
        mmn = fminf(mmn, fminf(fminf(fminf(m0.x, m0.y), fminf(m0.z, m0.w)),
                               fminf(fminf(m1.x, m1.y), fminf(m1.z, m1.w))));
        mmn = fminf(mmn, fminf(fminf(fminf(m2.x, m2.y), fminf(m2.z, m2.w)),
                               fminf(fminf(m3.x, m3.y), fminf(m3.z, m3.w))));
        mmx = fmaxf(mmx, fmaxf(fmaxf(fmaxf(m0.x, m0.y), fmaxf(m0.z, m0.w)),
                               fmaxf(fmaxf(m1.x, m1.y), fmaxf(m1.z, m1.w))));
        mmx = fmaxf(mmx, fmaxf(fmaxf(fmaxf(m2.x, m2.y), fmaxf(m2.z, m2.w)),
                               fmaxf(fmaxf(m3.x, m3.y), fmaxf(m3.z, m3.w))));
    }
    for (; i < nvec; i += T) {
        float4 f = f4[i];
        float4 m = m4[i];
        fmn = fminf(fmn, fminf(fminf(f.x, f.y), fminf(f.z, f.w)));
        fmx = fmaxf(fmx, fmaxf(fmaxf(f.x, f.y), fmaxf(f.z, f.w)));
        mmn = fminf(mmn, fminf(fminf(m.x, m.y), fminf(m.z, m.w)));
        mmx = fmaxf(mmx, fmaxf(fmaxf(m.x, m.y), fmaxf(m.z, m.w)));
    }
    // wave reduce (64 lanes)
    for (int d = 32; d; d >>= 1) {
        fmn = fminf(fmn, __shfl_xor(fmn, d));
        fmx = fmaxf(fmx, __shfl_xor(fmx, d));
        mmn = fminf(mmn, __shfl_xor(mmn, d));
        mmx = fmaxf(mmx, __shfl_xor(mmx, d));
    }
    __shared__ float4 wred[16];
    int wid = t >> 6, lane = t & 63;
    if (lane == 0) wred[wid] = make_float4(fmn, fmx, mmn, mmx);
    __syncthreads();
    if (wid == 0) {
        float4 s = wred[lane & 15];
        for (int d = 8; d; d >>= 1) {
            s.x = fminf(s.x, __shfl_xor(s.x, d));
            s.y = fmaxf(s.y, __shfl_xor(s.y, d));
            s.z = fminf(s.z, __shfl_xor(s.z, d));
            s.w = fmaxf(s.w, __shfl_xor(s.w, d));
        }
        if (lane == 0) ws->slot[b * GX + bx] = s;
    }
}

__global__ __launch_bounds__(BT) void k_hist(const float4* __restrict__ mov,
                                             const float4* __restrict__ fix,
                                             WS* __restrict__ ws, int nvec) {
    __shared__ ull ldsJ[8][256];          // 8 copies, 2 waves each (16 KB)
    __shared__ unsigned int ldsF[16][NB]; // per-wave fixed counts (1 KB)
    __shared__ float4 mmbc;
    int t = threadIdx.x;
    int b = blockIdx.y, bx = blockIdx.x;

    for (int i = t; i < 8 * 256; i += BT) ((ull*)ldsJ)[i] = 0ull;
    if (t < 16 * NB) ((unsigned int*)ldsF)[t] = 0u;

    // reduce per-block minmax slots (first wave)
    if (t < 64) {
        float4 s = ws->slot[b * GX + (t & (GX - 1))];
        for (int d = 32; d; d >>= 1) {
            s.x = fminf(s.x, __shfl_xor(s.x, d));
            s.y = fmaxf(s.y, __shfl_xor(s.y, d));
            s.z = fminf(s.z, __shfl_xor(s.z, d));
            s.w = fmaxf(s.w, __shfl_xor(s.w, d));
        }
        if (t == 0) mmbc = s;
    }
    __syncthreads();

    float fbs = (mmbc.y - mmbc.x) / 12.0f;   // nb - 2*PADDING
    float mbs = (mmbc.w - mmbc.z) / 12.0f;
    float fsh = mmbc.x / fbs - 2.0f;         // PADDING
    float msh = mmbc.z / mbs - 2.0f;

    int copy = t >> 7;   // 0..7
    int wid = t >> 6;    // 0..15
    const float4* m4 = mov + (size_t)b * nvec;
    const float4* f4 = fix + (size_t)b * nvec;
    int T = gridDim.x * BT;

    auto proc = [&](float fv, float mv) {
        float fterm = fv / fbs - fsh;        // exact div: keep bit-identical to reference
        int fi = (int)fterm;
        fi = fi < 2 ? 2 : (fi > NB - 3 ? NB - 3 : fi);
        float mterm = mv / mbs - msh;
        int mi_ = (int)mterm;
        mi_ = mi_ < 2 ? 2 : (mi_ > NB - 3 ? NB - 3 : mi_);
        atomicAdd(&ldsF[wid][fi], 1u);
        float b0 = (float)(mi_ - 1) - mterm;
        int baseIdx = fi * NB + mi_ - 1;
#pragma unroll
        for (int k = 0; k < 4; k++) {
            float u = b0 + (float)k;
            float au = fabsf(u);
            float su = au * au;
            float w;
            if (au < 1.0f)
                w = (4.0f - 6.0f * su + 3.0f * su * au) * (1.0f / 6.0f);
            else if (au < 2.0f)
                w = (8.0f - 12.0f * au + 6.0f * su - su * au) * (1.0f / 6.0f);
            else
                w = 0.0f;
            w = fmaxf(w, 0.0f);
            ull q = (ull)((double)w * 4294967296.0);
            atomicAdd(&ldsJ[copy][baseIdx + k], q);
        }
    };

    int i = bx * BT + t;
    for (; i + T < nvec; i += 2 * T) {
        float4 f0 = f4[i], f1 = f4[i + T];
        float4 m0 = m4[i], m1 = m4[i + T];
        proc(f0.x, m0.x); proc(f0.y, m0.y); proc(f0.z, m0.z); proc(f0.w, m0.w);
        proc(f1.x, m1.x); proc(f1.y, m1.y); proc(f1.z, m1.z); proc(f1.w, m1.w);
    }
    for (; i < nvec; i += T) {
        float4 fv = f4[i];
        float4 mv = m4[i];
        proc(fv.x, mv.x); proc(fv.y, mv.y); proc(fv.z, mv.z); proc(fv.w, mv.w);
    }
    __syncthreads();

    if (t < 256) {
        ull v = 0;
#pragma unroll
        for (int c = 0; c < 8; c++) v += ldsJ[c][t];
        if (v) atomicAdd(&ws->joint[b * 256 + t], v);
    } else if (t < 256 + NB) {
        int f = t - 256;
        unsigned int c = 0;
#pragma unroll
        for (int w = 0; w < 16; w++) c += ldsF[w][f];
        if (c) atomicAdd(&ws->fcount[b * NB + f], c);
    }
}

__global__ __launch_bounds__(1024) void k_final(const WS* __restrict__ ws,
                                                float* __restrict__ out, double invN) {
    __shared__ double shp[1024];
    __shared__ double red[1024];
    int t = threadIdx.x;
    int b = t >> 8;
    int bin = t & 255;

    double jt = (double)ws->joint[b * 256 + bin];
    red[t] = jt;
    __syncthreads();
    for (int s = 128; s > 0; s >>= 1) {
        if (bin < s) red[t] += red[t + s];
        __syncthreads();
    }
    double total = red[b * 256];
    __syncthreads();

    double p = jt / total;
    shp[t] = p;
    __syncthreads();

    double val = (p > 0.0) ? p * log(p) : 0.0;
    if (bin < NB) {
        double mp = 0.0;
        for (int f = 0; f < NB; f++) mp += shp[b * 256 + f * NB + bin];
        if (mp > 0.0) val -= mp * log(mp);
        double fp = (double)ws->fcount[b * NB + bin] * invN;
        if (fp > 0.0) val -= fp * log(fp);
    }
    __syncthreads();
    red[t] = val;
    __syncthreads();
    for (int s = 128; s > 0; s >>= 1) {
        if (bin < s) red[t] += red[t + s];
        __syncthreads();
    }
    if (t == 0) {
        double acc = red[0] + red[256] + red[512] + red[768];
        out[0] = (float)(-acc / (double)BATCHES);
    }
}

extern "C" void kernel_launch(void* const* d_in, const int* in_sizes, int n_in,
                              void* d_out, int out_size, void* d_ws, size_t ws_size,
                              hipStream_t stream) {
    const float* mov = (const float*)d_in[0];
    const float* fix = (const float*)d_in[1];
    float* out = (float*)d_out;
    WS* ws = (WS*)d_ws;

    int total = in_sizes[0];
    int N = total / BATCHES;      // 128^3
    int nvec = N / 4;

    dim3 grid(GX, BATCHES);
    k_minmax<<<grid, BT, 0, stream>>>((const float4*)mov, (const float4*)fix, ws, nvec);
    k_hist<<<grid, BT, 0, stream>>>((const float4*)mov, (const float4*)fix, ws, nvec);
    k_final<<<1, 1024, 0, stream>>>(ws, out, 1.0 / (double)N);
}

// Round 8
// 121.532 us; speedup vs baseline: 1.7920x; 1.2317x over previous
//
#include <hip/hip_runtime.h>

#define NB 16
#define BATCHES 4
#define GX 128           // blocks per batch -> 512 total = 2 blocks/CU on 256 CUs
#define BT 1024          // 16 waves/block -> 32 waves/CU (max occupancy)

typedef unsigned long long ull;

struct WS {
    float4 slot[BATCHES * GX];     // per-block {fmin, fmax, mmin, mmax}
    ull joint[BATCHES * 256];      // swizzled fixed-point (x 2^32) joint histogram
};

__global__ __launch_bounds__(BT) void k_minmax(const float4* __restrict__ mov,
                                               const float4* __restrict__ fix,
                                               WS* __restrict__ ws, int nvec) {
    int t = threadIdx.x;
    int b = blockIdx.y, bx = blockIdx.x;
    // block (0,0) zeroes the joint accumulators (d_ws is poisoned before each launch)
    if (bx == 0 && b == 0) ws->joint[t] = 0ull;   // exactly 1024 entries

    const float4* m4 = mov + (size_t)b * nvec;
    const float4* f4 = fix + (size_t)b * nvec;
    int T = gridDim.x * BT;
    int i = bx * BT + t;
    float fmn = 3.4e38f, fmx = -3.4e38f, mmn = 3.4e38f, mmx = -3.4e38f;
    for (; i + 3 * T < nvec; i += 4 * T) {
        float4 f0 = f4[i], f1 = f4[i + T], f2 = f4[i + 2 * T], f3 = f4[i + 3 * T];
        float4 m0 = m4[i], m1 = m4[i + T], m2 = m4[i + 2 * T], m3 = m4[i + 3 * T];
        fmn = fminf(fmn, fminf(fminf(fminf(f0.x, f0.y), fminf(f0.z, f0.w)),
                               fminf(fminf(f1.x, f1.y), fminf(f1.z, f1.w))));
        fmn = fminf(fmn, fminf(fminf(fminf(f2.x, f2.y), fminf(f2.z, f2.w)),
                               fminf(fminf(f3.x, f3.y), fminf(f3.z, f3.w))));
        fmx = fmaxf(fmx, fmaxf(fmaxf(fmaxf(f0.x, f0.y), fmaxf(f0.z, f0.w)),
                               fmaxf(fmaxf(f1.x, f1.y), fmaxf(f1.z, f1.w))));
        fmx = fmaxf(fmx, fmaxf(fmaxf(fmaxf(f2.x, f2.y), fmaxf(f2.z, f2.w)),
                               fmaxf(fmaxf(f3.x, f3.y), fmaxf(f3.z, f3.w))));
        mmn = fminf(mmn, fminf(fminf(fminf(m0.x, m0.y), fminf(m0.z, m0.w)),
                               fminf(fminf(m1.x, m1.y), fminf(m1.z, m1.w))));
        mmn = fminf(mmn, fminf(fminf(fminf(m2.x, m2.y), fminf(m2.z, m2.w)),
                               fminf(fminf(m3.x, m3.y), fminf(m3.z, m3.w))));
        mmx = fmaxf(mmx, fmaxf(fmaxf(fmaxf(m0.x, m0.y), fmaxf(m0.z, m0.w)),
                               fmaxf(fmaxf(m1.x, m1.y), fmaxf(m1.z, m1.w))));
        mmx = fmaxf(mmx, fmaxf(fmaxf(fmaxf(m2.x, m2.y), fmaxf(m2.z, m2.w)),
                               fmaxf(fmaxf(m3.x, m3.y), fmaxf(m3.z, m3.w))));
    }
    for (; i < nvec; i += T) {
        float4 f = f4[i];
        float4 m = m4[i];
        fmn = fminf(fmn, fminf(fminf(f.x, f.y), fminf(f.z, f.w)));
        fmx = fmaxf(fmx, fmaxf(fmaxf(f.x, f.y), fmaxf(f.z, f.w)));
        mmn = fminf(mmn, fminf(fminf(m.x, m.y), fminf(m.z, m.w)));
        mmx = fmaxf(mmx, fmaxf(fmaxf(m.x, m.y), fmaxf(m.z, m.w)));
    }
    for (int d = 32; d; d >>= 1) {
        fmn = fminf(fmn, __shfl_xor(fmn, d));
        fmx = fmaxf(fmx, __shfl_xor(fmx, d));
        mmn = fminf(mmn, __shfl_xor(mmn, d));
        mmx = fmaxf(mmx, __shfl_xor(mmx, d));
    }
    __shared__ float4 wred[16];
    int wid = t >> 6, lane = t & 63;
    if (lane == 0) wred[wid] = make_float4(fmn, fmx, mmn, mmx);
    __syncthreads();
    if (wid == 0) {
        float4 s = wred[lane & 15];
        for (int d = 8; d; d >>= 1) {
            s.x = fminf(s.x, __shfl_xor(s.x, d));
            s.y = fmaxf(s.y, __shfl_xor(s.y, d));
            s.z = fminf(s.z, __shfl_xor(s.z, d));
            s.w = fmaxf(s.w, __shfl_xor(s.w, d));
        }
        if (lane == 0) ws->slot[b * GX + bx] = s;
    }
}

__global__ __launch_bounds__(BT) void k_hist(const float4* __restrict__ mov,
                                             const float4* __restrict__ fix,
                                             WS* __restrict__ ws, int nvec) {
    __shared__ ull ldsJ[16][256];   // one private copy per wave (32 KB)
    __shared__ float4 mmbc;
    int t = threadIdx.x;
    int b = blockIdx.y, bx = blockIdx.x;
    int wid = t >> 6;

    // zero: 4096 u64 / 1024 thr = 4 each
    #pragma unroll
    for (int i = 0; i < 4; i++) ((ull*)ldsJ)[t + i * BT] = 0ull;

    // reduce the 128 per-block minmax slots (first wave: 2 slots per lane)
    if (t < 64) {
        float4 a = ws->slot[b * GX + t];
        float4 c = ws->slot[b * GX + t + 64];
        float4 s = make_float4(fminf(a.x, c.x), fmaxf(a.y, c.y),
                               fminf(a.z, c.z), fmaxf(a.w, c.w));
        for (int d = 32; d; d >>= 1) {
            s.x = fminf(s.x, __shfl_xor(s.x, d));
            s.y = fmaxf(s.y, __shfl_xor(s.y, d));
            s.z = fminf(s.z, __shfl_xor(s.z, d));
            s.w = fmaxf(s.w, __shfl_xor(s.w, d));
        }
        if (t == 0) mmbc = s;
    }
    __syncthreads();

    float fbs = (mmbc.y - mmbc.x) * (1.0f / 12.0f);   // (nb - 2*PADDING)
    float mbs = (mmbc.w - mmbc.z) * (1.0f / 12.0f);
    float finv = 1.0f / fbs;
    float minv = 1.0f / mbs;
    float fofs = __builtin_fmaf(-mmbc.x, finv, 2.0f); // fterm = fv*finv + fofs
    float mofs = __builtin_fmaf(-mmbc.z, minv, 2.0f);

    ull* myJ = &ldsJ[wid][0];
    const float4* m4 = mov + (size_t)b * nvec;
    const float4* f4 = fix + (size_t)b * nvec;
    int T = gridDim.x * BT;

    auto proc = [&](float fv, float mv) {
        float fterm = __builtin_fmaf(fv, finv, fofs);
        int fi = (int)fterm;
        fi = fi < 2 ? 2 : (fi > NB - 3 ? NB - 3 : fi);
        float mterm = __builtin_fmaf(mv, minv, mofs);
        int mi_ = (int)mterm;
        mi_ = mi_ < 2 ? 2 : (mi_ > NB - 3 ? NB - 3 : mi_);
        float tt = mterm - (float)mi_;
        tt = fminf(fmaxf(tt, 0.0f), 1.0f);            // guard epsilon over/undershoot
        // cubic B-spline basis (partition of unity)
        float t2 = tt * tt;
        float omt = 1.0f - tt;
        float w0 = omt * omt * omt * (1.0f / 6.0f);                       // off=-1
        float w3 = tt * t2 * (1.0f / 6.0f);                               // off=+2
        float w1 = __builtin_fmaf(__builtin_fmaf(3.0f, tt, -6.0f), t2, 4.0f) * (1.0f / 6.0f); // off=0
        float w2 = 1.0f - w0 - w1 - w3;                                   // off=+1
        // swizzled slot: row fi, column (mcol + 5*fi) & 15 spreads bank pairs
        int row = fi << 4;
        int s0 = (mi_ - 1 + 5 * fi) & 15;
        atomicAdd(myJ + row + s0,             (ull)(unsigned int)(w0 * 4294967296.0f));
        atomicAdd(myJ + row + ((s0 + 1) & 15), (ull)(unsigned int)(w1 * 4294967296.0f));
        atomicAdd(myJ + row + ((s0 + 2) & 15), (ull)(unsigned int)(w2 * 4294967296.0f));
        atomicAdd(myJ + row + ((s0 + 3) & 15), (ull)(unsigned int)(w3 * 4294967296.0f));
    };

    int i = bx * BT + t;
    for (; i + T < nvec; i += 2 * T) {
        float4 f0 = f4[i], f1 = f4[i + T];
        float4 m0 = m4[i], m1 = m4[i + T];
        proc(f0.x, m0.x); proc(f0.y, m0.y); proc(f0.z, m0.z); proc(f0.w, m0.w);
        proc(f1.x, m1.x); proc(f1.y, m1.y); proc(f1.z, m1.z); proc(f1.w, m1.w);
    }
    for (; i < nvec; i += T) {
        float4 fv = f4[i];
        float4 mv = m4[i];
        proc(fv.x, mv.x); proc(fv.y, mv.y); proc(fv.z, mv.z); proc(fv.w, mv.w);
    }
    __syncthreads();

    // flush: threads 0..255 sum the 16 wave copies for their bin
    if (t < 256) {
        ull v = 0;
        #pragma unroll
        for (int c = 0; c < 16; c++) v += ldsJ[c][t];
        if (v) atomicAdd(&ws->joint[b * 256 + t], v);
    }
}

__global__ __launch_bounds__(256) void k_final(const WS* __restrict__ ws,
                                               float* __restrict__ out) {
    __shared__ double shp[256];
    __shared__ double wsum[4];
    int t = threadIdx.x, lane = t & 63, wid = t >> 6;
    double acc = 0.0;
    for (int b = 0; b < BATCHES; ++b) {
        ull q = ws->joint[b * 256 + t];
        double v = (double)q;
        double s = v;
        for (int d = 32; d; d >>= 1) s += __shfl_xor(s, d);
        if (lane == 0) wsum[wid] = s;
        __syncthreads();
        double total = wsum[0] + wsum[1] + wsum[2] + wsum[3];
        double p = v / total;
        // de-swizzle: slot t = (f, c) holds bin (f, m) with m = (c - 5f) & 15
        int f = t >> 4, c = t & 15, m = (c - 5 * f) & 15;
        __syncthreads();                 // prior-iter shp reads complete
        shp[f * 16 + m] = p;
        double val = (q != 0ull) ? p * log(p) : 0.0;
        __syncthreads();
        if (t < 16) {                    // movingPDF: column sums over f
            double mp = 0.0;
            #pragma unroll
            for (int f2 = 0; f2 < 16; ++f2) mp += shp[f2 * 16 + t];
            if (mp > 0.0) val -= mp * log(mp);
        } else if (t < 32) {             // fixedPDF: row sums over m (partition of unity)
            int f2 = t - 16;
            double fp = 0.0;
            #pragma unroll
            for (int m2 = 0; m2 < 16; ++m2) fp += shp[f2 * 16 + m2];
            if (fp > 0.0) val -= fp * log(fp);
        }
        double s2 = val;
        for (int d = 32; d; d >>= 1) s2 += __shfl_xor(s2, d);
        __syncthreads();
        if (lane == 0) wsum[wid] = s2;
        __syncthreads();
        if (t == 0) acc += wsum[0] + wsum[1] + wsum[2] + wsum[3];
        __syncthreads();
    }
    if (t == 0) out[0] = (float)(-acc / (double)BATCHES);
}

extern "C" void kernel_launch(void* const* d_in, const int* in_sizes, int n_in,
                              void* d_out, int out_size, void* d_ws, size_t ws_size,
                              hipStream_t stream) {
    const float* mov = (const float*)d_in[0];
    const float* fix = (const float*)d_in[1];
    float* out = (float*)d_out;
    WS* ws = (WS*)d_ws;

    int total = in_sizes[0];
    int N = total / BATCHES;      // 128^3
    int nvec = N / 4;

    dim3 grid(GX, BATCHES);
    k_minmax<<<grid, BT, 0, stream>>>((const float4*)mov, (const float4*)fix, ws, nvec);
    k_hist<<<grid, BT, 0, stream>>>((const float4*)mov, (const float4*)fix, ws, nvec);
    k_final<<<1, 256, 0, stream>>>(ws, out);
}